// Round 6
// baseline (204.360 us; speedup 1.0000x reference)
//
#include <hip/hip_runtime.h>

#define BATCH 128
#define VIS   98
#define TOK   196
#define TOK2  392
#define ENC   1024
#define DEC   512
#define MSK   294   // 2*TOK - VIS

#define NWB 256        // (DEC*ENC/4) float4s / 512 threads
#define GEMM_BLKS 784  // 4 n-tiles x 196 m-tiles
#define FILL_BLKS 240  // grid-stride fill blocks -> total 1024 = 4/CU

typedef __bf16 bf16x8 __attribute__((ext_vector_type(8)));
typedef float  f32x4  __attribute__((ext_vector_type(4)));

__device__ __forceinline__ unsigned short f2bf(float f) {
    union { float f; unsigned u; } c; c.f = f;
    unsigned u = c.u;
    return (unsigned short)((u + 0x7fffu + ((u >> 16) & 1u)) >> 16);
}

__device__ __forceinline__ bf16x8 cvt8(f32x4 lo, f32x4 hi) {
    bf16x8 r;
    r[0] = (__bf16)lo[0]; r[1] = (__bf16)lo[1]; r[2] = (__bf16)lo[2]; r[3] = (__bf16)lo[3];
    r[4] = (__bf16)hi[0]; r[5] = (__bf16)hi[1]; r[6] = (__bf16)hi[2]; r[7] = (__bf16)hi[3];
    return r;
}

// async global -> LDS, 16 B per lane; LDS dest must be wave-uniform base + lane*16
__device__ __forceinline__ void g2lds16(const void* gptr, void* lptr) {
    __builtin_amdgcn_global_load_lds(
        (const __attribute__((address_space(1))) void*)gptr,
        (__attribute__((address_space(3))) void*)lptr, 16, 0, 0);
}

// Small setup: blocks [0,NWB): W fp32->bf16 ; blocks [NWB, NWB+BATCH): build map
__global__ __launch_bounds__(512) void setup(const float* __restrict__ W,
                                             const int* __restrict__ mids,
                                             unsigned short* __restrict__ wbm,
                                             int* __restrict__ visids,
                                             unsigned char* __restrict__ flags) {
    int bid = blockIdx.x, tid = threadIdx.x;
    if (bid < NWB) {
        int i = bid * 512 + tid;
        float4 f = ((const float4*)W)[i];
        ushort4 o;
        o.x = f2bf(f.x); o.y = f2bf(f.y); o.z = f2bf(f.z); o.w = f2bf(f.w);
        ((ushort4*)wbm)[i] = o;
        return;
    }
    int b = bid - NWB;
    __shared__ unsigned char lf[TOK2];
    __shared__ int wtot[8];
    if (tid < TOK2) lf[tid] = 1;
    __syncthreads();
    if (tid < MSK) lf[mids[b * MSK + tid]] = 0;
    __syncthreads();
    int flag = (tid < TOK2) ? (int)lf[tid] : 0;
    unsigned long long bal = __ballot(flag != 0);
    int lane = tid & 63, wv = tid >> 6;
    int pre = __popcll(bal & ((1ull << lane) - 1ull));
    if (lane == 0) wtot[wv] = __popcll(bal);
    __syncthreads();
    int off = 0;
    for (int i = 0; i < wv; ++i) off += wtot[i];
    if (flag) visids[b * VIS + off + pre] = tid;   // stable: ascending token id
    if (tid < TOK2) flags[b * TOK2 + tid] = lf[tid];
}

// Fused: blocks [0, GEMM_BLKS): 64m x 128n GEMM tiles (A fp32 from x, cvt at frag read)
//        blocks [GEMM_BLKS, +FILL_BLKS): grid-stride masked-token fill
// GEMM: BK=64, 4 waves 2x2 (wave = 32m x 64n, acc[2][4]).
// A LDS: 64 rows x 256 B (16 chunks), slot = c ^ (row&15)  -> <=2-way conflicts
// B LDS: 128 rows x 128 B (8 chunks),  slot = c ^ (row&7)
// mfma_f32_16x16x32_bf16: A lane: row=l&15, k=(l>>4)*8+j ; B lane: col=l&15, same k;
// D lane: col=l&15, row=(l>>4)*4+reg   [m89-verified layout]
__global__ __launch_bounds__(256, 4) void gemm_fill(
    const float* __restrict__ x,             // (B*V, ENC) fp32
    const unsigned short* __restrict__ wb,   // (DEC, ENC) bf16 bits
    const float* __restrict__ bias,
    const float* __restrict__ mask_token,
    const float* __restrict__ pos,
    const float* __restrict__ ve,
    const int* __restrict__ vis,             // (B*V) -> t
    const unsigned char* __restrict__ flags, // (B*392) 1=visible
    float* __restrict__ out) {
    __shared__ float          As[64 * 64];   // 16 KB
    __shared__ unsigned short Bs[128 * 64];  // 16 KB
    __shared__ int rowdst[64];
    __shared__ int rowt[64];

    int bid = blockIdx.x, tid = threadIdx.x;

    if (bid >= GEMM_BLKS) {                  // ---- fill path ----
        int fb = bid - GEMM_BLKS;
        int d4 = tid & 127, sub = tid >> 7;
        float4 m = ((const float4*)mask_token)[d4];
        for (int row = fb * 2 + sub; row < BATCH * TOK2; row += FILL_BLKS * 2) {
            if (flags[row]) continue;        // visible -> gemm writes it
            int t = row % TOK2;
            float4 p = ((const float4*)(pos + (size_t)t * DEC))[d4];
            float4 v = ((const float4*)(ve + (t >= TOK ? DEC : 0)))[d4];
            float4 r;
            r.x = m.x + p.x + v.x;
            r.y = m.y + p.y + v.y;
            r.z = m.z + p.z + v.z;
            r.w = m.w + p.w + v.w;
            ((float4*)(out + (size_t)row * DEC))[d4] = r;
        }
        return;
    }

    // ---- gemm path ----
    int lane = tid & 63, w = tid >> 6;
    int l16 = lane & 15, q = lane >> 4;
    int wm = w & 1, wn = w >> 1;
    int n0 = (bid & 3) * 128, m0 = (bid >> 2) * 64;

    if (tid < 64) {
        int gr = m0 + tid;
        int t = vis[gr];
        rowt[tid] = t;
        rowdst[tid] = (gr / VIS) * TOK2 + t;
    }

    // A staging: thread -> row (tid>>4), slot (tid&15); global chunk c = slot ^ (row&15)
    int rA = tid >> 4;
    int cA = (tid & 15) ^ (rA & 15);
    const float* gA = x + (size_t)(m0 + rA) * ENC + cA * 4;
    // B staging: thread -> row (tid>>3), slot (tid&7); global chunk c = slot ^ (row&7)
    int rB = tid >> 3;
    int cB = (tid & 7) ^ (rB & 7);
    const unsigned short* gB = wb + (size_t)(n0 + rB) * ENC + cB * 8;
    char* ldsA = (char*)As + tid * 16;
    char* ldsB = (char*)Bs + tid * 16;

    f32x4 acc[2][4];
    #pragma unroll
    for (int i = 0; i < 2; ++i)
        #pragma unroll
        for (int j = 0; j < 4; ++j)
            acc[i][j] = (f32x4){0.f, 0.f, 0.f, 0.f};

    for (int k0 = 0; k0 < ENC; k0 += 64) {
        __syncthreads();
        #pragma unroll
        for (int t = 0; t < 4; ++t)          // A: 64 rows x 64 k fp32 (16 rows/call)
            g2lds16(gA + (size_t)t * 16 * ENC + k0, ldsA + t * 4096);
        #pragma unroll
        for (int t = 0; t < 4; ++t)          // B: 128 rows x 64 k bf16 (32 rows/call)
            g2lds16(gB + (size_t)t * 32 * ENC + k0, ldsB + t * 4096);
        __syncthreads();

        #pragma unroll
        for (int u = 0; u < 2; ++u) {        // two k32 substeps
            int slotB = ((u * 4 + q) ^ (l16 & 7)) * 16;
            bf16x8 bfrag[4];
            #pragma unroll
            for (int j = 0; j < 4; ++j)
                bfrag[j] = *(const bf16x8*)((const char*)Bs + (wn * 64 + j * 16 + l16) * 128 + slotB);
            bf16x8 afrag[2];
            #pragma unroll
            for (int i = 0; i < 2; ++i) {
                int ar = wm * 32 + i * 16 + l16;
                int p0 = ((u * 8 + 2 * q) ^ l16) * 16;
                int p1 = ((u * 8 + 2 * q + 1) ^ l16) * 16;
                f32x4 lo = *(const f32x4*)((const char*)As + ar * 256 + p0);
                f32x4 hi = *(const f32x4*)((const char*)As + ar * 256 + p1);
                afrag[i] = cvt8(lo, hi);
            }
            #pragma unroll
            for (int i = 0; i < 2; ++i)
                #pragma unroll
                for (int j = 0; j < 4; ++j)
                    acc[i][j] = __builtin_amdgcn_mfma_f32_16x16x32_bf16(afrag[i], bfrag[j], acc[i][j], 0, 0, 0);
        }
    }

    // epilogue: +bias +pos +view_embed, scatter rows to out[b, t, :]
    #pragma unroll
    for (int j = 0; j < 4; ++j) {
        int gcol = n0 + wn * 64 + j * 16 + l16;
        float bc = bias[gcol];
        float v0 = ve[gcol];
        float v1 = ve[DEC + gcol];
        #pragma unroll
        for (int i = 0; i < 2; ++i) {
            #pragma unroll
            for (int r = 0; r < 4; ++r) {
                int rl = wm * 32 + i * 16 + q * 4 + r;
                int t = rowt[rl];
                float val = acc[i][j][r] + bc + pos[(size_t)t * DEC + gcol]
                          + (t >= TOK ? v1 : v0);
                out[(size_t)rowdst[rl] * DEC + gcol] = val;
            }
        }
    }
}

extern "C" void kernel_launch(void* const* d_in, const int* in_sizes, int n_in,
                              void* d_out, int out_size, void* d_ws, size_t ws_size,
                              hipStream_t stream) {
    (void)in_sizes; (void)n_in; (void)out_size; (void)ws_size;
    const float* x    = (const float*)d_in[0];
    const int*   mids = (const int*)d_in[1];
    const float* W    = (const float*)d_in[2];
    const float* bias = (const float*)d_in[3];
    const float* mt   = (const float*)d_in[4];
    const float* pos  = (const float*)d_in[5];
    const float* ve   = (const float*)d_in[6];
    float* out = (float*)d_out;

    // workspace: W bf16 (1 MB) + maps
    unsigned short* wbm = (unsigned short*)d_ws;                     // DEC*ENC bf16
    int* visids = (int*)(wbm + (size_t)DEC * ENC);                   // B*V int
    unsigned char* flags = (unsigned char*)(visids + BATCH * VIS);   // B*392 bytes

    hipLaunchKernelGGL(setup, dim3(NWB + BATCH), dim3(512), 0, stream,
                       W, mids, wbm, visids, flags);
    hipLaunchKernelGGL(gemm_fill, dim3(GEMM_BLKS + FILL_BLKS), dim3(256), 0, stream,
                       x, wbm, bias, mt, pos, ve, visids, flags, out);
}